// Round 1
// baseline (3840.310 us; speedup 1.0000x reference)
//
#include <hip/hip_runtime.h>

#define N_NODES 50000
#define N_EDGES 800000
#define IN_F 96
#define H_F 256
#define N_NIE 4

// ---------------- degree / dinv ----------------
__global__ __launch_bounds__(256) void k_deg(const int* __restrict__ rows,
                                             const int* __restrict__ cols,
                                             float* __restrict__ deg) {
    int e = blockIdx.x * 256 + threadIdx.x;
    if (e >= N_EDGES) return;
    int r = rows[e], c = cols[e];
    if (r != c) atomicAdd(&deg[r], 1.0f);
}

__global__ __launch_bounds__(256) void k_dinv(float* __restrict__ deg) {
    int i = blockIdx.x * 256 + threadIdx.x;
    if (i >= N_NODES) return;
    deg[i] = 1.0f / sqrtf(deg[i] + 1.0f);  // self-loop adds 1; always > 0
}

// ---------------- row-normalize features (wave per node) ----------------
__global__ __launch_bounds__(256) void k_norm(const float* __restrict__ feat,
                                              float* __restrict__ x) {
    int wid = (blockIdx.x * 256 + threadIdx.x) >> 6;
    int lane = threadIdx.x & 63;
    if (wid >= N_NODES) return;
    const float* fr = feat + (size_t)wid * IN_F;
    float v0 = (lane < IN_F) ? fr[lane] : 0.0f;
    float v1 = (lane < IN_F - 64) ? fr[64 + lane] : 0.0f;
    float ss = v0 * v0 + v1 * v1;
    #pragma unroll
    for (int o = 32; o; o >>= 1) ss += __shfl_xor(ss, o, 64);
    float inv = 1.0f / fmaxf(sqrtf(ss), 1e-12f);
    float* xr = x + (size_t)wid * IN_F;
    if (lane < IN_F) xr[lane] = v0 * inv;
    if (lane < IN_F - 64) xr[64 + lane] = v1 * inv;
}

// ---------------- self-loop init: h_next = dinv^2 * h ----------------
__global__ __launch_bounds__(256) void k_selfloop(const float* __restrict__ h,
                                                  const float* __restrict__ dinv,
                                                  float* __restrict__ hn) {
    int idx = blockIdx.x * 256 + threadIdx.x;  // over N_NODES*24 float4s
    if (idx >= N_NODES * 24) return;
    int node = idx / 24;
    float d = dinv[node];
    float w = d * d;
    float4 v = ((const float4*)h)[idx];
    v.x *= w; v.y *= w; v.z *= w; v.w *= w;
    ((float4*)hn)[idx] = v;
}

// ---------------- edge-parallel SpMM scatter ----------------
__global__ __launch_bounds__(256) void k_spmm(const int* __restrict__ rows,
                                              const int* __restrict__ cols,
                                              const float* __restrict__ dinv,
                                              const float* __restrict__ h,
                                              float* __restrict__ hn) {
    int idx = blockIdx.x * 256 + threadIdx.x;  // over N_EDGES*24
    if (idx >= N_EDGES * 24) return;
    int e = idx / 24, j = idx - e * 24;
    int r = rows[e], c = cols[e];
    if (r == c) return;  // set_diag zeroed pre-existing diagonal entries
    float w = dinv[r] * dinv[c];
    float4 v = ((const float4*)(h + (size_t)c * IN_F))[j];
    float* dst = hn + (size_t)r * IN_F + j * 4;
    atomicAdd(dst + 0, v.x * w);
    atomicAdd(dst + 1, v.y * w);
    atomicAdd(dst + 2, v.z * w);
    atomicAdd(dst + 3, v.w * w);
}

// ---------------- per-hop MLP: ns = relu(A @ W + b), A[M x 96], W[96 x 256] ----------------
__global__ __launch_bounds__(256) void k_mlp(const float* __restrict__ A,
                                             const float* __restrict__ W,
                                             const float* __restrict__ b,
                                             float* __restrict__ out) {
    __shared__ float As[64][100];  // pad 96 -> 100 (bank-conflict-free)
    __shared__ float Bs[96][64];
    int m0 = blockIdx.x * 64, n0 = blockIdx.y * 64;
    int tid = threadIdx.x;
    #pragma unroll
    for (int i = 0; i < 24; ++i) {
        int flat = tid + i * 256;  // 0..6143
        int m = flat / 96, k = flat - m * 96;
        int gm = m0 + m;
        As[m][k] = (gm < N_NODES) ? A[(size_t)gm * IN_F + k] : 0.0f;
    }
    {
        int j = tid & 63, k0 = tid >> 6;
        #pragma unroll
        for (int k = k0; k < 96; k += 4) Bs[k][j] = W[k * H_F + n0 + j];
    }
    __syncthreads();
    int tx = tid & 15, ty = tid >> 4;
    float acc[4][4] = {};
    #pragma unroll 4
    for (int k = 0; k < 96; ++k) {
        float a0 = As[ty * 4 + 0][k], a1 = As[ty * 4 + 1][k];
        float a2 = As[ty * 4 + 2][k], a3 = As[ty * 4 + 3][k];
        float4 bv = *(const float4*)&Bs[k][tx * 4];
        acc[0][0] += a0 * bv.x; acc[0][1] += a0 * bv.y; acc[0][2] += a0 * bv.z; acc[0][3] += a0 * bv.w;
        acc[1][0] += a1 * bv.x; acc[1][1] += a1 * bv.y; acc[1][2] += a1 * bv.z; acc[1][3] += a1 * bv.w;
        acc[2][0] += a2 * bv.x; acc[2][1] += a2 * bv.y; acc[2][2] += a2 * bv.z; acc[2][3] += a2 * bv.w;
        acc[3][0] += a3 * bv.x; acc[3][1] += a3 * bv.y; acc[3][2] += a3 * bv.z; acc[3][3] += a3 * bv.w;
    }
    float4 bb = *(const float4*)&b[n0 + tx * 4];
    #pragma unroll
    for (int i = 0; i < 4; ++i) {
        int gm = m0 + ty * 4 + i;
        if (gm < N_NODES) {
            float4 o;
            o.x = fmaxf(acc[i][0] + bb.x, 0.0f);
            o.y = fmaxf(acc[i][1] + bb.y, 0.0f);
            o.z = fmaxf(acc[i][2] + bb.z, 0.0f);
            o.w = fmaxf(acc[i][3] + bb.w, 0.0f);
            *(float4*)&out[(size_t)gm * H_F + n0 + tx * 4] = o;
        }
    }
}

// ---------------- fusion GEMM accumulate: acc += A @ W, A[M x 256], W[256 x 256] ----------------
__global__ __launch_bounds__(256) void k_fuse(const float* __restrict__ A,
                                              const float* __restrict__ W,
                                              float* __restrict__ accOut) {
    __shared__ float As[64][33];
    __shared__ float Bs[32][64];
    int m0 = blockIdx.x * 64, n0 = blockIdx.y * 64;
    int tid = threadIdx.x;
    int tx = tid & 15, ty = tid >> 4;
    float acc[4][4] = {};
    for (int kc = 0; kc < 256; kc += 32) {
        {
            int k = tid & 31, mr0 = tid >> 5;  // 8 rows/pass
            #pragma unroll
            for (int m = mr0; m < 64; m += 8) {
                int gm = m0 + m;
                As[m][k] = (gm < N_NODES) ? A[(size_t)gm * H_F + kc + k] : 0.0f;
            }
        }
        {
            int j = tid & 63, k0 = tid >> 6;
            #pragma unroll
            for (int k = k0; k < 32; k += 4) Bs[k][j] = W[(size_t)(kc + k) * H_F + n0 + j];
        }
        __syncthreads();
        #pragma unroll 8
        for (int k = 0; k < 32; ++k) {
            float a0 = As[ty * 4 + 0][k], a1 = As[ty * 4 + 1][k];
            float a2 = As[ty * 4 + 2][k], a3 = As[ty * 4 + 3][k];
            float4 bv = *(const float4*)&Bs[k][tx * 4];
            acc[0][0] += a0 * bv.x; acc[0][1] += a0 * bv.y; acc[0][2] += a0 * bv.z; acc[0][3] += a0 * bv.w;
            acc[1][0] += a1 * bv.x; acc[1][1] += a1 * bv.y; acc[1][2] += a1 * bv.z; acc[1][3] += a1 * bv.w;
            acc[2][0] += a2 * bv.x; acc[2][1] += a2 * bv.y; acc[2][2] += a2 * bv.z; acc[2][3] += a2 * bv.w;
            acc[3][0] += a3 * bv.x; acc[3][1] += a3 * bv.y; acc[3][2] += a3 * bv.z; acc[3][3] += a3 * bv.w;
        }
        __syncthreads();
    }
    #pragma unroll
    for (int i = 0; i < 4; ++i) {
        int gm = m0 + ty * 4 + i;
        if (gm < N_NODES) {
            float* p = &accOut[(size_t)gm * H_F + n0 + tx * 4];
            float4 old = *(float4*)p;
            old.x += acc[i][0]; old.y += acc[i][1]; old.z += acc[i][2]; old.w += acc[i][3];
            *(float4*)p = old;
        }
    }
}

// ---------------- bias init / final relu ----------------
__global__ __launch_bounds__(256) void k_bias(const float* __restrict__ bf,
                                              float* __restrict__ acc) {
    int idx = blockIdx.x * 256 + threadIdx.x;  // over N_NODES*64 float4s
    if (idx >= N_NODES * 64) return;
    ((float4*)acc)[idx] = ((const float4*)bf)[idx & 63];
}

__global__ __launch_bounds__(256) void k_relu(float* __restrict__ acc) {
    int idx = blockIdx.x * 256 + threadIdx.x;
    if (idx >= N_NODES * 64) return;
    float4 v = ((float4*)acc)[idx];
    v.x = fmaxf(v.x, 0.0f); v.y = fmaxf(v.y, 0.0f);
    v.z = fmaxf(v.z, 0.0f); v.w = fmaxf(v.w, 0.0f);
    ((float4*)acc)[idx] = v;
}

extern "C" void kernel_launch(void* const* d_in, const int* in_sizes, int n_in,
                              void* d_out, int out_size, void* d_ws, size_t ws_size,
                              hipStream_t stream) {
    const int* ei = (const int*)d_in[0];
    const int* rows = ei;
    const int* cols = ei + N_EDGES;
    const float* feat = (const float*)d_in[1];
    const float* Ws = (const float*)d_in[2];
    const float* bs = (const float*)d_in[3];
    const float* Wf = (const float*)d_in[4];
    const float* bf = (const float*)d_in[5];
    float* out = (float*)d_out;

    float* hA = (float*)d_ws;              // 4.8M floats
    float* hB = hA + (size_t)N_NODES * IN_F;
    float* ns = hB + (size_t)N_NODES * IN_F;  // 12.8M floats
    float* dinv = ns + (size_t)N_NODES * H_F; // 50k floats (deg first)

    hipMemsetAsync(dinv, 0, N_NODES * sizeof(float), stream);
    k_deg<<<(N_EDGES + 255) / 256, 256, 0, stream>>>(rows, cols, dinv);
    k_dinv<<<(N_NODES + 255) / 256, 256, 0, stream>>>(dinv);
    k_norm<<<(N_NODES + 3) / 4, 256, 0, stream>>>(feat, hA);
    k_bias<<<(N_NODES * 64 + 255) / 256, 256, 0, stream>>>(bf, out);

    float* hcur = hA;
    float* hnext = hB;
    for (int i = 0; i < N_NIE; ++i) {
        k_mlp<<<dim3(782, 4), 256, 0, stream>>>(hcur, Ws + (size_t)i * IN_F * H_F,
                                                bs + (size_t)i * H_F, ns);
        k_fuse<<<dim3(782, 4), 256, 0, stream>>>(ns, Wf + (size_t)i * H_F * H_F, out);
        if (i < N_NIE - 1) {
            k_selfloop<<<(N_NODES * 24 + 255) / 256, 256, 0, stream>>>(hcur, dinv, hnext);
            k_spmm<<<(N_EDGES * 24 + 255) / 256, 256, 0, stream>>>(rows, cols, dinv, hcur, hnext);
            float* t = hcur; hcur = hnext; hnext = t;
        }
    }
    k_relu<<<(N_NODES * 64 + 255) / 256, 256, 0, stream>>>(out);
}

// Round 2
// 1112.724 us; speedup vs baseline: 3.4513x; 3.4513x over previous
//
#include <hip/hip_runtime.h>

#define N_NODES 50000
#define N_EDGES 800000
#define IN_F 96
#define H_F 256
#define N_NIE 4

// ---------------- CSR build: count / scan / scatter ----------------
__global__ __launch_bounds__(256) void k_count(const int* __restrict__ rows,
                                               const int* __restrict__ cols,
                                               int* __restrict__ cnt) {
    int e = blockIdx.x * 256 + threadIdx.x;
    if (e >= N_EDGES) return;
    int r = rows[e];
    if (r != cols[e]) atomicAdd(&cnt[r], 1);
}

__global__ __launch_bounds__(1024) void k_scan(const int* __restrict__ cnt,
                                               int* __restrict__ rowptr,
                                               int* __restrict__ cursor) {
    __shared__ int part[1024];
    int t = threadIdx.x;
    const int CH = (N_NODES + 1023) / 1024;  // 49
    int st = t * CH, en = min(st + CH, N_NODES);
    int s = 0;
    for (int i = st; i < en; ++i) s += cnt[i];
    part[t] = s;
    __syncthreads();
    for (int off = 1; off < 1024; off <<= 1) {
        int v = (t >= off) ? part[t - off] : 0;
        __syncthreads();
        part[t] += v;
        __syncthreads();
    }
    int run = (t > 0) ? part[t - 1] : 0;
    for (int i = st; i < en; ++i) {
        rowptr[i] = run;
        cursor[i] = run;
        run += cnt[i];
    }
    if (t == 1023) rowptr[N_NODES] = part[1023];
}

__global__ __launch_bounds__(256) void k_dinv(const int* __restrict__ cnt,
                                              float* __restrict__ dinv) {
    int i = blockIdx.x * 256 + threadIdx.x;
    if (i >= N_NODES) return;
    dinv[i] = rsqrtf((float)cnt[i] + 1.0f);  // self-loop adds 1; always > 0
}

__global__ __launch_bounds__(256) void k_scatter(const int* __restrict__ rows,
                                                 const int* __restrict__ cols,
                                                 int* __restrict__ cursor,
                                                 int* __restrict__ ccol) {
    int e = blockIdx.x * 256 + threadIdx.x;
    if (e >= N_EDGES) return;
    int r = rows[e], c = cols[e];
    if (r == c) return;  // set_diag zeroes pre-existing diagonal entries
    int p = atomicAdd(&cursor[r], 1);
    ccol[p] = c;
}

// ---------------- row-normalize features (wave per node) ----------------
__global__ __launch_bounds__(256) void k_norm(const float* __restrict__ feat,
                                              float* __restrict__ x) {
    int wid = (blockIdx.x * 256 + threadIdx.x) >> 6;
    int lane = threadIdx.x & 63;
    if (wid >= N_NODES) return;
    const float* fr = feat + (size_t)wid * IN_F;
    float v0 = (lane < IN_F) ? fr[lane] : 0.0f;
    float v1 = (lane < IN_F - 64) ? fr[64 + lane] : 0.0f;
    float ss = v0 * v0 + v1 * v1;
    #pragma unroll
    for (int o = 32; o; o >>= 1) ss += __shfl_xor(ss, o, 64);
    float inv = 1.0f / fmaxf(sqrtf(ss), 1e-12f);
    float* xr = x + (size_t)wid * IN_F;
    if (lane < IN_F) xr[lane] = v0 * inv;
    if (lane < IN_F - 64) xr[64 + lane] = v1 * inv;
}

// ---------------- CSR SpMM: 32-lane group per row, self-loop fused ----------------
__global__ __launch_bounds__(256) void k_spmm_csr(const int* __restrict__ rowptr,
                                                  const int* __restrict__ ccol,
                                                  const float* __restrict__ dinv,
                                                  const float* __restrict__ x,
                                                  float* __restrict__ y) {
    int g = (blockIdx.x * 256 + threadIdx.x) >> 5;  // one 32-lane group per row
    if (g >= N_NODES) return;
    int l = threadIdx.x & 31;  // lane handles feats [3l, 3l+2]
    float dr = dinv[g];
    float a0, a1, a2;
    {
        float w = dr * dr;  // self-loop term
        const float* xs = x + (size_t)g * IN_F + l * 3;
        a0 = xs[0] * w; a1 = xs[1] * w; a2 = xs[2] * w;
    }
    int b = rowptr[g], e = rowptr[g + 1];
    for (int k = b; k < e; ++k) {
        int c = ccol[k];                 // broadcast across the 32 lanes
        float w = dr * dinv[c];
        const float* xs = x + (size_t)c * IN_F + l * 3;
        a0 += xs[0] * w; a1 += xs[1] * w; a2 += xs[2] * w;
    }
    float* yr = y + (size_t)g * IN_F + l * 3;
    yr[0] = a0; yr[1] = a1; yr[2] = a2;
}

// ---------------- per-hop MLP: ns = relu(A @ W + b), A[M x 96], W[96 x 256] ----------------
__global__ __launch_bounds__(256) void k_mlp(const float* __restrict__ A,
                                             const float* __restrict__ W,
                                             const float* __restrict__ b,
                                             float* __restrict__ out) {
    __shared__ float As[64][100];  // pad 96 -> 100 (bank-conflict-free)
    __shared__ float Bs[96][64];
    int m0 = blockIdx.x * 64, n0 = blockIdx.y * 64;
    int tid = threadIdx.x;
    #pragma unroll
    for (int i = 0; i < 24; ++i) {
        int flat = tid + i * 256;  // 0..6143
        int m = flat / 96, k = flat - m * 96;
        int gm = m0 + m;
        As[m][k] = (gm < N_NODES) ? A[(size_t)gm * IN_F + k] : 0.0f;
    }
    {
        int j = tid & 63, k0 = tid >> 6;
        #pragma unroll
        for (int k = k0; k < 96; k += 4) Bs[k][j] = W[k * H_F + n0 + j];
    }
    __syncthreads();
    int tx = tid & 15, ty = tid >> 4;
    float acc[4][4] = {};
    #pragma unroll 4
    for (int k = 0; k < 96; ++k) {
        float a0 = As[ty * 4 + 0][k], a1 = As[ty * 4 + 1][k];
        float a2 = As[ty * 4 + 2][k], a3 = As[ty * 4 + 3][k];
        float4 bv = *(const float4*)&Bs[k][tx * 4];
        acc[0][0] += a0 * bv.x; acc[0][1] += a0 * bv.y; acc[0][2] += a0 * bv.z; acc[0][3] += a0 * bv.w;
        acc[1][0] += a1 * bv.x; acc[1][1] += a1 * bv.y; acc[1][2] += a1 * bv.z; acc[1][3] += a1 * bv.w;
        acc[2][0] += a2 * bv.x; acc[2][1] += a2 * bv.y; acc[2][2] += a2 * bv.z; acc[2][3] += a2 * bv.w;
        acc[3][0] += a3 * bv.x; acc[3][1] += a3 * bv.y; acc[3][2] += a3 * bv.z; acc[3][3] += a3 * bv.w;
    }
    float4 bb = *(const float4*)&b[n0 + tx * 4];
    #pragma unroll
    for (int i = 0; i < 4; ++i) {
        int gm = m0 + ty * 4 + i;
        if (gm < N_NODES) {
            float4 o;
            o.x = fmaxf(acc[i][0] + bb.x, 0.0f);
            o.y = fmaxf(acc[i][1] + bb.y, 0.0f);
            o.z = fmaxf(acc[i][2] + bb.z, 0.0f);
            o.w = fmaxf(acc[i][3] + bb.w, 0.0f);
            *(float4*)&out[(size_t)gm * H_F + n0 + tx * 4] = o;
        }
    }
}

// ---------------- fusion GEMM accumulate: acc += A @ W, A[M x 256], W[256 x 256] ----------------
__global__ __launch_bounds__(256) void k_fuse(const float* __restrict__ A,
                                              const float* __restrict__ W,
                                              float* __restrict__ accOut) {
    __shared__ float As[64][33];
    __shared__ float Bs[32][64];
    int m0 = blockIdx.x * 64, n0 = blockIdx.y * 64;
    int tid = threadIdx.x;
    int tx = tid & 15, ty = tid >> 4;
    float acc[4][4] = {};
    for (int kc = 0; kc < 256; kc += 32) {
        {
            int k = tid & 31, mr0 = tid >> 5;  // 8 rows/pass
            #pragma unroll
            for (int m = mr0; m < 64; m += 8) {
                int gm = m0 + m;
                As[m][k] = (gm < N_NODES) ? A[(size_t)gm * H_F + kc + k] : 0.0f;
            }
        }
        {
            int j = tid & 63, k0 = tid >> 6;
            #pragma unroll
            for (int k = k0; k < 32; k += 4) Bs[k][j] = W[(size_t)(kc + k) * H_F + n0 + j];
        }
        __syncthreads();
        #pragma unroll 8
        for (int k = 0; k < 32; ++k) {
            float a0 = As[ty * 4 + 0][k], a1 = As[ty * 4 + 1][k];
            float a2 = As[ty * 4 + 2][k], a3 = As[ty * 4 + 3][k];
            float4 bv = *(const float4*)&Bs[k][tx * 4];
            acc[0][0] += a0 * bv.x; acc[0][1] += a0 * bv.y; acc[0][2] += a0 * bv.z; acc[0][3] += a0 * bv.w;
            acc[1][0] += a1 * bv.x; acc[1][1] += a1 * bv.y; acc[1][2] += a1 * bv.z; acc[1][3] += a1 * bv.w;
            acc[2][0] += a2 * bv.x; acc[2][1] += a2 * bv.y; acc[2][2] += a2 * bv.z; acc[2][3] += a2 * bv.w;
            acc[3][0] += a3 * bv.x; acc[3][1] += a3 * bv.y; acc[3][2] += a3 * bv.z; acc[3][3] += a3 * bv.w;
        }
        __syncthreads();
    }
    #pragma unroll
    for (int i = 0; i < 4; ++i) {
        int gm = m0 + ty * 4 + i;
        if (gm < N_NODES) {
            float* p = &accOut[(size_t)gm * H_F + n0 + tx * 4];
            float4 old = *(float4*)p;
            old.x += acc[i][0]; old.y += acc[i][1]; old.z += acc[i][2]; old.w += acc[i][3];
            *(float4*)p = old;
        }
    }
}

// ---------------- bias init / final relu ----------------
__global__ __launch_bounds__(256) void k_bias(const float* __restrict__ bf,
                                              float* __restrict__ acc) {
    int idx = blockIdx.x * 256 + threadIdx.x;  // over N_NODES*64 float4s
    if (idx >= N_NODES * 64) return;
    ((float4*)acc)[idx] = ((const float4*)bf)[idx & 63];
}

__global__ __launch_bounds__(256) void k_relu(float* __restrict__ acc) {
    int idx = blockIdx.x * 256 + threadIdx.x;
    if (idx >= N_NODES * 64) return;
    float4 v = ((float4*)acc)[idx];
    v.x = fmaxf(v.x, 0.0f); v.y = fmaxf(v.y, 0.0f);
    v.z = fmaxf(v.z, 0.0f); v.w = fmaxf(v.w, 0.0f);
    ((float4*)acc)[idx] = v;
}

extern "C" void kernel_launch(void* const* d_in, const int* in_sizes, int n_in,
                              void* d_out, int out_size, void* d_ws, size_t ws_size,
                              hipStream_t stream) {
    const int* ei = (const int*)d_in[0];
    const int* rows = ei;
    const int* cols = ei + N_EDGES;
    const float* feat = (const float*)d_in[1];
    const float* Ws = (const float*)d_in[2];
    const float* bs = (const float*)d_in[3];
    const float* Wf = (const float*)d_in[4];
    const float* bf = (const float*)d_in[5];
    float* out = (float*)d_out;

    // workspace layout (~93 MB)
    float* hA = (float*)d_ws;                      // 50000*96
    float* hB = hA + (size_t)N_NODES * IN_F;       // 50000*96
    float* ns = hB + (size_t)N_NODES * IN_F;       // 50000*256
    float* dinv = ns + (size_t)N_NODES * H_F;      // 50000
    int* rowptr = (int*)(dinv + N_NODES);          // 50001 (rounded to 50004)
    int* csr_col = rowptr + 50004;                 // 800000
    // temporaries aliased into ns (only live before the hop loop):
    int* cnt = (int*)ns;                           // 50000
    int* cursor = cnt + N_NODES;                   // 50000

    // ---- CSR build + dinv ----
    hipMemsetAsync(cnt, 0, N_NODES * sizeof(int), stream);
    k_count<<<(N_EDGES + 255) / 256, 256, 0, stream>>>(rows, cols, cnt);
    k_scan<<<1, 1024, 0, stream>>>(cnt, rowptr, cursor);
    k_dinv<<<(N_NODES + 255) / 256, 256, 0, stream>>>(cnt, dinv);
    k_scatter<<<(N_EDGES + 255) / 256, 256, 0, stream>>>(rows, cols, cursor, csr_col);

    k_norm<<<(N_NODES + 3) / 4, 256, 0, stream>>>(feat, hA);
    k_bias<<<(N_NODES * 64 + 255) / 256, 256, 0, stream>>>(bf, out);

    float* hcur = hA;
    float* hnext = hB;
    for (int i = 0; i < N_NIE; ++i) {
        k_mlp<<<dim3(782, 4), 256, 0, stream>>>(hcur, Ws + (size_t)i * IN_F * H_F,
                                                bs + (size_t)i * H_F, ns);
        k_fuse<<<dim3(782, 4), 256, 0, stream>>>(ns, Wf + (size_t)i * H_F * H_F, out);
        if (i < N_NIE - 1) {
            k_spmm_csr<<<(N_NODES * 32 + 255) / 256, 256, 0, stream>>>(rowptr, csr_col, dinv,
                                                                       hcur, hnext);
            float* t = hcur; hcur = hnext; hnext = t;
        }
    }
    k_relu<<<(N_NODES * 64 + 255) / 256, 256, 0, stream>>>(out);
}

// Round 3
// 784.773 us; speedup vs baseline: 4.8935x; 1.4179x over previous
//
#include <hip/hip_runtime.h>

#define N_NODES 50000
#define N_EDGES 800000
#define IN_F 96
#define H_F 256
#define N_NIE 4

typedef float f32x4 __attribute__((ext_vector_type(4)));
typedef short s16x8 __attribute__((ext_vector_type(8)));
typedef unsigned short u16x4 __attribute__((ext_vector_type(4)));
typedef unsigned short ushort;

__device__ __forceinline__ ushort bf16_rne(float f) {
    unsigned u = __float_as_uint(f);
    u += 0x7fffu + ((u >> 16) & 1u);
    return (ushort)(u >> 16);
}
__device__ __forceinline__ float bf16_f(ushort h) {
    return __uint_as_float(((unsigned)h) << 16);
}

// ---------------- CSR build: count / scan / scatter ----------------
__global__ __launch_bounds__(256) void k_count(const int* __restrict__ rows,
                                               const int* __restrict__ cols,
                                               int* __restrict__ cnt) {
    int e = blockIdx.x * 256 + threadIdx.x;
    if (e >= N_EDGES) return;
    int r = rows[e];
    if (r != cols[e]) atomicAdd(&cnt[r], 1);
}

__global__ __launch_bounds__(1024) void k_scan(const int* __restrict__ cnt,
                                               int* __restrict__ rowptr,
                                               int* __restrict__ cursor) {
    __shared__ int part[1024];
    int t = threadIdx.x;
    const int CH = (N_NODES + 1023) / 1024;  // 49
    int st = t * CH, en = min(st + CH, N_NODES);
    int s = 0;
    for (int i = st; i < en; ++i) s += cnt[i];
    part[t] = s;
    __syncthreads();
    for (int off = 1; off < 1024; off <<= 1) {
        int v = (t >= off) ? part[t - off] : 0;
        __syncthreads();
        part[t] += v;
        __syncthreads();
    }
    int run = (t > 0) ? part[t - 1] : 0;
    for (int i = st; i < en; ++i) {
        rowptr[i] = run;
        cursor[i] = run;
        run += cnt[i];
    }
    if (t == 1023) rowptr[N_NODES] = part[1023];
}

__global__ __launch_bounds__(256) void k_dinv(const int* __restrict__ cnt,
                                              float* __restrict__ dinv) {
    int i = blockIdx.x * 256 + threadIdx.x;
    if (i >= N_NODES) return;
    dinv[i] = rsqrtf((float)cnt[i] + 1.0f);
}

__global__ __launch_bounds__(256) void k_scatter(const int* __restrict__ rows,
                                                 const int* __restrict__ cols,
                                                 int* __restrict__ cursor,
                                                 int* __restrict__ ccol) {
    int e = blockIdx.x * 256 + threadIdx.x;
    if (e >= N_EDGES) return;
    int r = rows[e], c = cols[e];
    if (r == c) return;  // set_diag zeroes pre-existing diagonal entries
    int p = atomicAdd(&cursor[r], 1);
    ccol[p] = c;
}

// ---------------- weight transpose + split: dst[g][n][k] = split(src[g][k][n]) ----------------
__global__ __launch_bounds__(256) void k_wsplit(const float* __restrict__ src,
                                                ushort* __restrict__ dh,
                                                ushort* __restrict__ dl,
                                                int K, int N, int total) {
    int idx = blockIdx.x * 256 + threadIdx.x;
    if (idx >= total) return;
    int kn = K * N;
    int g = idx / kn, rem = idx - g * kn;
    int k = rem / N, n = rem - k * N;
    float v = src[idx];
    ushort h = bf16_rne(v);
    ushort l = bf16_rne(v - bf16_f(h));
    int dst = g * kn + n * K + k;
    dh[dst] = h;
    dl[dst] = l;
}

// ---------------- row-normalize features (wave per node) ----------------
__global__ __launch_bounds__(256) void k_norm(const float* __restrict__ feat,
                                              float* __restrict__ x) {
    int wid = (blockIdx.x * 256 + threadIdx.x) >> 6;
    int lane = threadIdx.x & 63;
    if (wid >= N_NODES) return;
    const float* fr = feat + (size_t)wid * IN_F;
    float v0 = (lane < IN_F) ? fr[lane] : 0.0f;
    float v1 = (lane < IN_F - 64) ? fr[64 + lane] : 0.0f;
    float ss = v0 * v0 + v1 * v1;
    #pragma unroll
    for (int o = 32; o; o >>= 1) ss += __shfl_xor(ss, o, 64);
    float inv = 1.0f / fmaxf(sqrtf(ss), 1e-12f);
    float* xr = x + (size_t)wid * IN_F;
    if (lane < IN_F) xr[lane] = v0 * inv;
    if (lane < IN_F - 64) xr[64 + lane] = v1 * inv;
}

// ---------------- CSR SpMM: 32-lane group per row, self-loop fused ----------------
__global__ __launch_bounds__(256) void k_spmm_csr(const int* __restrict__ rowptr,
                                                  const int* __restrict__ ccol,
                                                  const float* __restrict__ dinv,
                                                  const float* __restrict__ x,
                                                  float* __restrict__ y) {
    int g = (blockIdx.x * 256 + threadIdx.x) >> 5;
    if (g >= N_NODES) return;
    int l = threadIdx.x & 31;  // lane handles feats [3l, 3l+2]
    float dr = dinv[g];
    float a0, a1, a2;
    {
        float w = dr * dr;  // self-loop
        const float* xs = x + (size_t)g * IN_F + l * 3;
        a0 = xs[0] * w; a1 = xs[1] * w; a2 = xs[2] * w;
    }
    int b = rowptr[g], e = rowptr[g + 1];
    for (int k = b; k < e; ++k) {
        int c = ccol[k];
        float w = dr * dinv[c];
        const float* xs = x + (size_t)c * IN_F + l * 3;
        a0 += xs[0] * w; a1 += xs[1] * w; a2 += xs[2] * w;
    }
    float* yr = y + (size_t)g * IN_F + l * 3;
    yr[0] = a0; yr[1] = a1; yr[2] = a2;
}

// ---------------- MFMA MLP: ns(split bf16) = relu(A[Mx96] @ WsT + b) ----------------
#define LDA1 104
__global__ __launch_bounds__(256) void k_mlp_mfma(const float* __restrict__ A,
                                                   const ushort* __restrict__ BTh,
                                                   const ushort* __restrict__ BTl,
                                                   const float* __restrict__ bias,
                                                   ushort* __restrict__ nsh,
                                                   ushort* __restrict__ nsl) {
    __shared__ ushort Ah[64 * LDA1], Al[64 * LDA1], Bh[64 * LDA1], Bl[64 * LDA1];
    int m0 = blockIdx.x * 64, n0 = blockIdx.y * 64;
    int tid = threadIdx.x;
    // stage A (fp32 -> hi/lo bf16): 64 rows x 24 float4
    #pragma unroll
    for (int p = 0; p < 6; ++p) {
        int flat = tid + p * 256;
        int r = flat / 24, j = flat - r * 24;
        int gm = m0 + r;
        float4 v = make_float4(0.f, 0.f, 0.f, 0.f);
        if (gm < N_NODES) v = *(const float4*)&A[(size_t)gm * IN_F + j * 4];
        float vv[4] = {v.x, v.y, v.z, v.w};
        u16x4 hh, ll;
        #pragma unroll
        for (int q = 0; q < 4; ++q) {
            ushort h = bf16_rne(vv[q]);
            hh[q] = h;
            ll[q] = bf16_rne(vv[q] - bf16_f(h));
        }
        *(u16x4*)&Ah[r * LDA1 + j * 4] = hh;
        *(u16x4*)&Al[r * LDA1 + j * 4] = ll;
    }
    // stage B (already split bf16, rows = out cols): 64 rows x 12 short8
    #pragma unroll
    for (int p = 0; p < 3; ++p) {
        int flat = tid + p * 256;
        int r = flat / 12, j = flat - r * 12;
        *(s16x8*)&Bh[r * LDA1 + j * 8] = *(const s16x8*)&BTh[(size_t)(n0 + r) * IN_F + j * 8];
        *(s16x8*)&Bl[r * LDA1 + j * 8] = *(const s16x8*)&BTl[(size_t)(n0 + r) * IN_F + j * 8];
    }
    __syncthreads();
    int lane = tid & 63, wid = tid >> 6;
    int wr = (wid >> 1) * 32, wc = (wid & 1) * 32;
    int rsel = lane & 15, ksel = (lane >> 4) * 8;
    f32x4 acc[2][2] = {};
    #pragma unroll
    for (int ks = 0; ks < 3; ++ks) {
        int k0 = ks * 32 + ksel;
        s16x8 a0h = *(const s16x8*)&Ah[(wr + rsel) * LDA1 + k0];
        s16x8 a1h = *(const s16x8*)&Ah[(wr + 16 + rsel) * LDA1 + k0];
        s16x8 a0l = *(const s16x8*)&Al[(wr + rsel) * LDA1 + k0];
        s16x8 a1l = *(const s16x8*)&Al[(wr + 16 + rsel) * LDA1 + k0];
        s16x8 b0h = *(const s16x8*)&Bh[(wc + rsel) * LDA1 + k0];
        s16x8 b1h = *(const s16x8*)&Bh[(wc + 16 + rsel) * LDA1 + k0];
        s16x8 b0l = *(const s16x8*)&Bl[(wc + rsel) * LDA1 + k0];
        s16x8 b1l = *(const s16x8*)&Bl[(wc + 16 + rsel) * LDA1 + k0];
        acc[0][0] = __builtin_amdgcn_mfma_f32_16x16x32_bf16(a0h, b0h, acc[0][0], 0, 0, 0);
        acc[0][0] = __builtin_amdgcn_mfma_f32_16x16x32_bf16(a0h, b0l, acc[0][0], 0, 0, 0);
        acc[0][0] = __builtin_amdgcn_mfma_f32_16x16x32_bf16(a0l, b0h, acc[0][0], 0, 0, 0);
        acc[0][1] = __builtin_amdgcn_mfma_f32_16x16x32_bf16(a0h, b1h, acc[0][1], 0, 0, 0);
        acc[0][1] = __builtin_amdgcn_mfma_f32_16x16x32_bf16(a0h, b1l, acc[0][1], 0, 0, 0);
        acc[0][1] = __builtin_amdgcn_mfma_f32_16x16x32_bf16(a0l, b1h, acc[0][1], 0, 0, 0);
        acc[1][0] = __builtin_amdgcn_mfma_f32_16x16x32_bf16(a1h, b0h, acc[1][0], 0, 0, 0);
        acc[1][0] = __builtin_amdgcn_mfma_f32_16x16x32_bf16(a1h, b0l, acc[1][0], 0, 0, 0);
        acc[1][0] = __builtin_amdgcn_mfma_f32_16x16x32_bf16(a1l, b0h, acc[1][0], 0, 0, 0);
        acc[1][1] = __builtin_amdgcn_mfma_f32_16x16x32_bf16(a1h, b1h, acc[1][1], 0, 0, 0);
        acc[1][1] = __builtin_amdgcn_mfma_f32_16x16x32_bf16(a1h, b1l, acc[1][1], 0, 0, 0);
        acc[1][1] = __builtin_amdgcn_mfma_f32_16x16x32_bf16(a1l, b1h, acc[1][1], 0, 0, 0);
    }
    int crow = (lane >> 4) * 4, ccol = lane & 15;
    #pragma unroll
    for (int mf = 0; mf < 2; ++mf)
        #pragma unroll
        for (int nf = 0; nf < 2; ++nf) {
            int col = n0 + wc + nf * 16 + ccol;
            float bb = bias[col];
            #pragma unroll
            for (int i = 0; i < 4; ++i) {
                int gm = m0 + wr + mf * 16 + crow + i;
                if (gm < N_NODES) {
                    float v = fmaxf(acc[mf][nf][i] + bb, 0.f);
                    ushort h = bf16_rne(v);
                    size_t o = (size_t)gm * H_F + col;
                    nsh[o] = h;
                    nsl[o] = bf16_rne(v - bf16_f(h));
                }
            }
        }
}

// ---------------- MFMA fusion: out[Mx256] += ns(split) @ WfT(split) ----------------
#define LDA2 72
__global__ __launch_bounds__(256) void k_fuse_mfma(const ushort* __restrict__ Ahg,
                                                    const ushort* __restrict__ Alg,
                                                    const ushort* __restrict__ BTh,
                                                    const ushort* __restrict__ BTl,
                                                    float* __restrict__ out) {
    __shared__ ushort Ah[64 * LDA2], Al[64 * LDA2], Bh[64 * LDA2], Bl[64 * LDA2];
    int m0 = blockIdx.x * 64, n0 = blockIdx.y * 64;
    int tid = threadIdx.x;
    int lane = tid & 63, wid = tid >> 6;
    int wr = (wid >> 1) * 32, wc = (wid & 1) * 32;
    int rsel = lane & 15, ksel = (lane >> 4) * 8;
    f32x4 acc[2][2] = {};
    for (int kc = 0; kc < H_F; kc += 64) {
        #pragma unroll
        for (int p = 0; p < 2; ++p) {
            int flat = tid + p * 256;  // short8 units, 8 per row
            int r = flat >> 3, j = flat & 7;
            int gm = m0 + r;
            s16x8 vh = {0, 0, 0, 0, 0, 0, 0, 0}, vl = vh;
            if (gm < N_NODES) {
                vh = *(const s16x8*)&Ahg[(size_t)gm * H_F + kc + j * 8];
                vl = *(const s16x8*)&Alg[(size_t)gm * H_F + kc + j * 8];
            }
            *(s16x8*)&Ah[r * LDA2 + j * 8] = vh;
            *(s16x8*)&Al[r * LDA2 + j * 8] = vl;
            *(s16x8*)&Bh[r * LDA2 + j * 8] = *(const s16x8*)&BTh[(size_t)(n0 + r) * H_F + kc + j * 8];
            *(s16x8*)&Bl[r * LDA2 + j * 8] = *(const s16x8*)&BTl[(size_t)(n0 + r) * H_F + kc + j * 8];
        }
        __syncthreads();
        #pragma unroll
        for (int ks = 0; ks < 2; ++ks) {
            int k0 = ks * 32 + ksel;
            s16x8 a0h = *(const s16x8*)&Ah[(wr + rsel) * LDA2 + k0];
            s16x8 a1h = *(const s16x8*)&Ah[(wr + 16 + rsel) * LDA2 + k0];
            s16x8 a0l = *(const s16x8*)&Al[(wr + rsel) * LDA2 + k0];
            s16x8 a1l = *(const s16x8*)&Al[(wr + 16 + rsel) * LDA2 + k0];
            s16x8 b0h = *(const s16x8*)&Bh[(wc + rsel) * LDA2 + k0];
            s16x8 b1h = *(const s16x8*)&Bh[(wc + 16 + rsel) * LDA2 + k0];
            s16x8 b0l = *(const s16x8*)&Bl[(wc + rsel) * LDA2 + k0];
            s16x8 b1l = *(const s16x8*)&Bl[(wc + 16 + rsel) * LDA2 + k0];
            acc[0][0] = __builtin_amdgcn_mfma_f32_16x16x32_bf16(a0h, b0h, acc[0][0], 0, 0, 0);
            acc[0][0] = __builtin_amdgcn_mfma_f32_16x16x32_bf16(a0h, b0l, acc[0][0], 0, 0, 0);
            acc[0][0] = __builtin_amdgcn_mfma_f32_16x16x32_bf16(a0l, b0h, acc[0][0], 0, 0, 0);
            acc[0][1] = __builtin_amdgcn_mfma_f32_16x16x32_bf16(a0h, b1h, acc[0][1], 0, 0, 0);
            acc[0][1] = __builtin_amdgcn_mfma_f32_16x16x32_bf16(a0h, b1l, acc[0][1], 0, 0, 0);
            acc[0][1] = __builtin_amdgcn_mfma_f32_16x16x32_bf16(a0l, b1h, acc[0][1], 0, 0, 0);
            acc[1][0] = __builtin_amdgcn_mfma_f32_16x16x32_bf16(a1h, b0h, acc[1][0], 0, 0, 0);
            acc[1][0] = __builtin_amdgcn_mfma_f32_16x16x32_bf16(a1h, b0l, acc[1][0], 0, 0, 0);
            acc[1][0] = __builtin_amdgcn_mfma_f32_16x16x32_bf16(a1l, b0h, acc[1][0], 0, 0, 0);
            acc[1][1] = __builtin_amdgcn_mfma_f32_16x16x32_bf16(a1h, b1h, acc[1][1], 0, 0, 0);
            acc[1][1] = __builtin_amdgcn_mfma_f32_16x16x32_bf16(a1h, b1l, acc[1][1], 0, 0, 0);
            acc[1][1] = __builtin_amdgcn_mfma_f32_16x16x32_bf16(a1l, b1h, acc[1][1], 0, 0, 0);
        }
        __syncthreads();
    }
    int crow = (lane >> 4) * 4, ccol = lane & 15;
    #pragma unroll
    for (int mf = 0; mf < 2; ++mf)
        #pragma unroll
        for (int nf = 0; nf < 2; ++nf) {
            int col = n0 + wc + nf * 16 + ccol;
            #pragma unroll
            for (int i = 0; i < 4; ++i) {
                int gm = m0 + wr + mf * 16 + crow + i;
                if (gm < N_NODES) out[(size_t)gm * H_F + col] += acc[mf][nf][i];
            }
        }
}

// ---------------- bias init / final relu ----------------
__global__ __launch_bounds__(256) void k_bias(const float* __restrict__ bf,
                                              float* __restrict__ acc) {
    int idx = blockIdx.x * 256 + threadIdx.x;
    if (idx >= N_NODES * 64) return;
    ((float4*)acc)[idx] = ((const float4*)bf)[idx & 63];
}

__global__ __launch_bounds__(256) void k_relu(float* __restrict__ acc) {
    int idx = blockIdx.x * 256 + threadIdx.x;
    if (idx >= N_NODES * 64) return;
    float4 v = ((float4*)acc)[idx];
    v.x = fmaxf(v.x, 0.0f); v.y = fmaxf(v.y, 0.0f);
    v.z = fmaxf(v.z, 0.0f); v.w = fmaxf(v.w, 0.0f);
    ((float4*)acc)[idx] = v;
}

extern "C" void kernel_launch(void* const* d_in, const int* in_sizes, int n_in,
                              void* d_out, int out_size, void* d_ws, size_t ws_size,
                              hipStream_t stream) {
    const int* ei = (const int*)d_in[0];
    const int* rows = ei;
    const int* cols = ei + N_EDGES;
    const float* feat = (const float*)d_in[1];
    const float* Ws = (const float*)d_in[2];
    const float* bs = (const float*)d_in[3];
    const float* Wf = (const float*)d_in[4];
    const float* bf = (const float*)d_in[5];
    float* out = (float*)d_out;

    // workspace layout (~95 MB, all 16B-aligned)
    float* hA = (float*)d_ws;                              // 4,800,000 f32
    float* hB = hA + (size_t)N_NODES * IN_F;               // 4,800,000 f32
    ushort* nsh = (ushort*)(hB + (size_t)N_NODES * IN_F);  // 12,800,000 u16
    ushort* nsl = nsh + (size_t)N_NODES * H_F;             // 12,800,000 u16
    ushort* WsTh = nsl + (size_t)N_NODES * H_F;            // 98,304 u16
    ushort* WsTl = WsTh + N_NIE * IN_F * H_F;
    ushort* WfTh = WsTl + N_NIE * IN_F * H_F;              // 262,144 u16
    ushort* WfTl = WfTh + N_NIE * H_F * H_F;
    float* dinv = (float*)(WfTl + N_NIE * H_F * H_F);      // 50,000 f32
    int* rowptr = (int*)(dinv + N_NODES);                  // 50,004 i32
    int* csr_col = rowptr + 50004;                         // 800,000 i32
    // CSR-build temporaries aliased into nsh (consumed before nsh is written)
    int* cnt = (int*)nsh;
    int* cursor = cnt + N_NODES;

    hipMemsetAsync(cnt, 0, N_NODES * sizeof(int), stream);
    k_count<<<(N_EDGES + 255) / 256, 256, 0, stream>>>(rows, cols, cnt);
    k_scan<<<1, 1024, 0, stream>>>(cnt, rowptr, cursor);
    k_dinv<<<(N_NODES + 255) / 256, 256, 0, stream>>>(cnt, dinv);
    k_scatter<<<(N_EDGES + 255) / 256, 256, 0, stream>>>(rows, cols, cursor, csr_col);
    k_wsplit<<<(N_NIE * IN_F * H_F + 255) / 256, 256, 0, stream>>>(Ws, WsTh, WsTl, IN_F, H_F,
                                                                   N_NIE * IN_F * H_F);
    k_wsplit<<<(N_NIE * H_F * H_F + 255) / 256, 256, 0, stream>>>(Wf, WfTh, WfTl, H_F, H_F,
                                                                  N_NIE * H_F * H_F);
    k_norm<<<(N_NODES + 3) / 4, 256, 0, stream>>>(feat, hA);
    k_bias<<<(N_NODES * 64 + 255) / 256, 256, 0, stream>>>(bf, out);

    float* hcur = hA;
    float* hnext = hB;
    for (int i = 0; i < N_NIE; ++i) {
        k_mlp_mfma<<<dim3(782, 4), 256, 0, stream>>>(hcur, WsTh + (size_t)i * IN_F * H_F,
                                                     WsTl + (size_t)i * IN_F * H_F,
                                                     bs + (size_t)i * H_F, nsh, nsl);
        k_fuse_mfma<<<dim3(782, 4), 256, 0, stream>>>(nsh, nsl, WfTh + (size_t)i * H_F * H_F,
                                                      WfTl + (size_t)i * H_F * H_F, out);
        if (i < N_NIE - 1) {
            k_spmm_csr<<<(N_NODES * 32 + 255) / 256, 256, 0, stream>>>(rowptr, csr_col, dinv,
                                                                       hcur, hnext);
            float* t = hcur; hcur = hnext; hnext = t;
        }
    }
    k_relu<<<(N_NODES * 64 + 255) / 256, 256, 0, stream>>>(out);
}

// Round 4
// 647.680 us; speedup vs baseline: 5.9293x; 1.2117x over previous
//
#include <hip/hip_runtime.h>

#define N_NODES 50000
#define N_EDGES 800000
#define IN_F 96
#define H_F 256
#define N_NIE 4
#define SCAN_NB 196  // ceil(50000/256)

typedef float f32x4 __attribute__((ext_vector_type(4)));
typedef short s16x8 __attribute__((ext_vector_type(8)));
typedef unsigned short u16x4 __attribute__((ext_vector_type(4)));
typedef unsigned short ushort;

__device__ __forceinline__ ushort bf16_rne(float f) {
    unsigned u = __float_as_uint(f);
    u += 0x7fffu + ((u >> 16) & 1u);
    return (ushort)(u >> 16);
}
__device__ __forceinline__ float bf16_f(ushort h) {
    return __uint_as_float(((unsigned)h) << 16);
}

// ---------------- CSR build ----------------
__global__ __launch_bounds__(256) void k_count(const int* __restrict__ rows,
                                               const int* __restrict__ cols,
                                               int* __restrict__ cnt) {
    int e = blockIdx.x * 256 + threadIdx.x;
    if (e >= N_EDGES) return;
    int r = rows[e];
    if (r != cols[e]) atomicAdd(&cnt[r], 1);
}

// phase 1: per-block exclusive scan of cnt, block totals to bsum
__global__ __launch_bounds__(256) void k_scan1(const int* __restrict__ cnt,
                                               int* __restrict__ rowptr,
                                               int* __restrict__ bsum) {
    __shared__ int s[256];
    int t = threadIdx.x, e = blockIdx.x * 256 + t;
    int v = (e < N_NODES) ? cnt[e] : 0;
    s[t] = v;
    __syncthreads();
    #pragma unroll
    for (int off = 1; off < 256; off <<= 1) {
        int nv = (t >= off) ? s[t - off] : 0;
        __syncthreads();
        s[t] += nv;
        __syncthreads();
    }
    if (e < N_NODES) rowptr[e] = s[t] - v;  // local exclusive
    if (t == 255) bsum[blockIdx.x] = s[255];
}

// phase 2: scan block sums (1 block), write grand total to rowptr[N]
__global__ __launch_bounds__(256) void k_scan2(int* __restrict__ bsum,
                                               int* __restrict__ boff,
                                               int* __restrict__ rowptr) {
    __shared__ int s[256];
    int t = threadIdx.x;
    int v = (t < SCAN_NB) ? bsum[t] : 0;
    s[t] = v;
    __syncthreads();
    #pragma unroll
    for (int off = 1; off < 256; off <<= 1) {
        int nv = (t >= off) ? s[t - off] : 0;
        __syncthreads();
        s[t] += nv;
        __syncthreads();
    }
    if (t < SCAN_NB) boff[t] = s[t] - v;
    if (t == 255) rowptr[N_NODES] = s[255];
}

// phase 3: add block offsets, init cursor
__global__ __launch_bounds__(256) void k_scan3(const int* __restrict__ boff,
                                               int* __restrict__ rowptr,
                                               int* __restrict__ cursor) {
    int e = blockIdx.x * 256 + threadIdx.x;
    if (e >= N_NODES) return;
    int r = rowptr[e] + boff[blockIdx.x];
    rowptr[e] = r;
    cursor[e] = r;
}

__global__ __launch_bounds__(256) void k_dinv(const int* __restrict__ cnt,
                                              float* __restrict__ dinv) {
    int i = blockIdx.x * 256 + threadIdx.x;
    if (i >= N_NODES) return;
    dinv[i] = rsqrtf((float)cnt[i] + 1.0f);
}

__global__ __launch_bounds__(256) void k_scatter(const int* __restrict__ rows,
                                                 const int* __restrict__ cols,
                                                 int* __restrict__ cursor,
                                                 int* __restrict__ ccol) {
    int e = blockIdx.x * 256 + threadIdx.x;
    if (e >= N_EDGES) return;
    int r = rows[e], c = cols[e];
    if (r == c) return;  // set_diag zeroes pre-existing diagonal entries
    int p = atomicAdd(&cursor[r], 1);
    ccol[p] = c;
}

// ---------------- weight transpose + split ----------------
__global__ __launch_bounds__(256) void k_wsplit(const float* __restrict__ src,
                                                ushort* __restrict__ dh,
                                                ushort* __restrict__ dl,
                                                int K, int N, int total) {
    int idx = blockIdx.x * 256 + threadIdx.x;
    if (idx >= total) return;
    int kn = K * N;
    int g = idx / kn, rem = idx - g * kn;
    int k = rem / N, n = rem - k * N;
    float v = src[idx];
    ushort h = bf16_rne(v);
    ushort l = bf16_rne(v - bf16_f(h));
    int dst = g * kn + n * K + k;
    dh[dst] = h;
    dl[dst] = l;
}

// ---------------- row-normalize features ----------------
__global__ __launch_bounds__(256) void k_norm(const float* __restrict__ feat,
                                              float* __restrict__ x) {
    int wid = (blockIdx.x * 256 + threadIdx.x) >> 6;
    int lane = threadIdx.x & 63;
    if (wid >= N_NODES) return;
    const float* fr = feat + (size_t)wid * IN_F;
    float v0 = (lane < IN_F) ? fr[lane] : 0.0f;
    float v1 = (lane < IN_F - 64) ? fr[64 + lane] : 0.0f;
    float ss = v0 * v0 + v1 * v1;
    #pragma unroll
    for (int o = 32; o; o >>= 1) ss += __shfl_xor(ss, o, 64);
    float inv = 1.0f / fmaxf(sqrtf(ss), 1e-12f);
    float* xr = x + (size_t)wid * IN_F;
    if (lane < IN_F) xr[lane] = v0 * inv;
    if (lane < IN_F - 64) xr[64 + lane] = v1 * inv;
}

// ---------------- CSR SpMM: 32-lane group/row, stride-32 coalesced ----------------
__global__ __launch_bounds__(256) void k_spmm_csr(const int* __restrict__ rowptr,
                                                  const int* __restrict__ ccol,
                                                  const float* __restrict__ dinv,
                                                  const float* __restrict__ x,
                                                  float* __restrict__ y) {
    int g = (blockIdx.x * 256 + threadIdx.x) >> 5;
    if (g >= N_NODES) return;
    int l = threadIdx.x & 31;  // lane handles feats l, l+32, l+64
    float dr = dinv[g];
    float a0, a1, a2;
    {
        float w = dr * dr;  // self-loop
        const float* xs = x + (size_t)g * IN_F;
        a0 = xs[l] * w; a1 = xs[l + 32] * w; a2 = xs[l + 64] * w;
    }
    int b = rowptr[g], e = rowptr[g + 1];
    for (int k = b; k < e; ++k) {
        int c = ccol[k];
        float w = dr * dinv[c];
        const float* xs = x + (size_t)c * IN_F;
        a0 += xs[l] * w; a1 += xs[l + 32] * w; a2 += xs[l + 64] * w;
    }
    float* yr = y + (size_t)g * IN_F;
    yr[l] = a0; yr[l + 32] = a1; yr[l + 64] = a2;
}

// ---------------- MFMA MLP: ns(split bf16) = relu(A[Mx96] @ WsT + b) ----------------
#define LDA1 104
__global__ __launch_bounds__(256) void k_mlp_mfma(const float* __restrict__ A,
                                                   const ushort* __restrict__ BTh,
                                                   const ushort* __restrict__ BTl,
                                                   const float* __restrict__ bias,
                                                   ushort* __restrict__ nsh,
                                                   ushort* __restrict__ nsl) {
    __shared__ ushort Ah[64 * LDA1], Al[64 * LDA1], Bh[64 * LDA1], Bl[64 * LDA1];
    int m0 = blockIdx.x * 64, n0 = blockIdx.y * 64;
    int tid = threadIdx.x;
    #pragma unroll
    for (int p = 0; p < 6; ++p) {
        int flat = tid + p * 256;
        int r = flat / 24, j = flat - r * 24;
        int gm = m0 + r;
        float4 v = make_float4(0.f, 0.f, 0.f, 0.f);
        if (gm < N_NODES) v = *(const float4*)&A[(size_t)gm * IN_F + j * 4];
        float vv[4] = {v.x, v.y, v.z, v.w};
        u16x4 hh, ll;
        #pragma unroll
        for (int q = 0; q < 4; ++q) {
            ushort h = bf16_rne(vv[q]);
            hh[q] = h;
            ll[q] = bf16_rne(vv[q] - bf16_f(h));
        }
        *(u16x4*)&Ah[r * LDA1 + j * 4] = hh;
        *(u16x4*)&Al[r * LDA1 + j * 4] = ll;
    }
    #pragma unroll
    for (int p = 0; p < 3; ++p) {
        int flat = tid + p * 256;
        int r = flat / 12, j = flat - r * 12;
        *(s16x8*)&Bh[r * LDA1 + j * 8] = *(const s16x8*)&BTh[(size_t)(n0 + r) * IN_F + j * 8];
        *(s16x8*)&Bl[r * LDA1 + j * 8] = *(const s16x8*)&BTl[(size_t)(n0 + r) * IN_F + j * 8];
    }
    __syncthreads();
    int lane = tid & 63, wid = tid >> 6;
    int wr = (wid >> 1) * 32, wc = (wid & 1) * 32;
    int rsel = lane & 15, ksel = (lane >> 4) * 8;
    f32x4 acc[2][2] = {};
    #pragma unroll
    for (int ks = 0; ks < 3; ++ks) {
        int k0 = ks * 32 + ksel;
        s16x8 a0h = *(const s16x8*)&Ah[(wr + rsel) * LDA1 + k0];
        s16x8 a1h = *(const s16x8*)&Ah[(wr + 16 + rsel) * LDA1 + k0];
        s16x8 a0l = *(const s16x8*)&Al[(wr + rsel) * LDA1 + k0];
        s16x8 a1l = *(const s16x8*)&Al[(wr + 16 + rsel) * LDA1 + k0];
        s16x8 b0h = *(const s16x8*)&Bh[(wc + rsel) * LDA1 + k0];
        s16x8 b1h = *(const s16x8*)&Bh[(wc + 16 + rsel) * LDA1 + k0];
        s16x8 b0l = *(const s16x8*)&Bl[(wc + rsel) * LDA1 + k0];
        s16x8 b1l = *(const s16x8*)&Bl[(wc + 16 + rsel) * LDA1 + k0];
        acc[0][0] = __builtin_amdgcn_mfma_f32_16x16x32_bf16(a0h, b0h, acc[0][0], 0, 0, 0);
        acc[0][0] = __builtin_amdgcn_mfma_f32_16x16x32_bf16(a0h, b0l, acc[0][0], 0, 0, 0);
        acc[0][0] = __builtin_amdgcn_mfma_f32_16x16x32_bf16(a0l, b0h, acc[0][0], 0, 0, 0);
        acc[0][1] = __builtin_amdgcn_mfma_f32_16x16x32_bf16(a0h, b1h, acc[0][1], 0, 0, 0);
        acc[0][1] = __builtin_amdgcn_mfma_f32_16x16x32_bf16(a0h, b1l, acc[0][1], 0, 0, 0);
        acc[0][1] = __builtin_amdgcn_mfma_f32_16x16x32_bf16(a0l, b1h, acc[0][1], 0, 0, 0);
        acc[1][0] = __builtin_amdgcn_mfma_f32_16x16x32_bf16(a1h, b0h, acc[1][0], 0, 0, 0);
        acc[1][0] = __builtin_amdgcn_mfma_f32_16x16x32_bf16(a1h, b0l, acc[1][0], 0, 0, 0);
        acc[1][0] = __builtin_amdgcn_mfma_f32_16x16x32_bf16(a1l, b0h, acc[1][0], 0, 0, 0);
        acc[1][1] = __builtin_amdgcn_mfma_f32_16x16x32_bf16(a1h, b1h, acc[1][1], 0, 0, 0);
        acc[1][1] = __builtin_amdgcn_mfma_f32_16x16x32_bf16(a1h, b1l, acc[1][1], 0, 0, 0);
        acc[1][1] = __builtin_amdgcn_mfma_f32_16x16x32_bf16(a1l, b1h, acc[1][1], 0, 0, 0);
    }
    int crow = (lane >> 4) * 4, ccol = lane & 15;
    #pragma unroll
    for (int mf = 0; mf < 2; ++mf)
        #pragma unroll
        for (int nf = 0; nf < 2; ++nf) {
            int col = n0 + wc + nf * 16 + ccol;
            float bb = bias[col];
            #pragma unroll
            for (int i = 0; i < 4; ++i) {
                int gm = m0 + wr + mf * 16 + crow + i;
                if (gm < N_NODES) {
                    float v = fmaxf(acc[mf][nf][i] + bb, 0.f);
                    ushort h = bf16_rne(v);
                    size_t o = (size_t)gm * H_F + col;
                    nsh[o] = h;
                    nsl[o] = bf16_rne(v - bf16_f(h));
                }
            }
        }
}

// ---------------- MFMA fusion: out = ns @ WfT (+bias / accum / +relu) ----------------
// MODE 0: out = acc + bias (no read of out);  1: out += acc;  2: out = relu(out + acc)
#define LDA2 72
template <int MODE>
__global__ __launch_bounds__(256) void k_fuse_mfma(const ushort* __restrict__ Ahg,
                                                    const ushort* __restrict__ Alg,
                                                    const ushort* __restrict__ BTh,
                                                    const ushort* __restrict__ BTl,
                                                    const float* __restrict__ bias,
                                                    float* __restrict__ out) {
    __shared__ ushort Ah[64 * LDA2], Al[64 * LDA2], Bh[64 * LDA2], Bl[64 * LDA2];
    int m0 = blockIdx.x * 64, n0 = blockIdx.y * 64;
    int tid = threadIdx.x;
    int lane = tid & 63, wid = tid >> 6;
    int wr = (wid >> 1) * 32, wc = (wid & 1) * 32;
    int rsel = lane & 15, ksel = (lane >> 4) * 8;
    f32x4 acc[2][2] = {};
    for (int kc = 0; kc < H_F; kc += 64) {
        #pragma unroll
        for (int p = 0; p < 2; ++p) {
            int flat = tid + p * 256;  // short8 units, 8 per row
            int r = flat >> 3, j = flat & 7;
            int gm = m0 + r;
            s16x8 vh = {0, 0, 0, 0, 0, 0, 0, 0}, vl = vh;
            if (gm < N_NODES) {
                vh = *(const s16x8*)&Ahg[(size_t)gm * H_F + kc + j * 8];
                vl = *(const s16x8*)&Alg[(size_t)gm * H_F + kc + j * 8];
            }
            *(s16x8*)&Ah[r * LDA2 + j * 8] = vh;
            *(s16x8*)&Al[r * LDA2 + j * 8] = vl;
            *(s16x8*)&Bh[r * LDA2 + j * 8] = *(const s16x8*)&BTh[(size_t)(n0 + r) * H_F + kc + j * 8];
            *(s16x8*)&Bl[r * LDA2 + j * 8] = *(const s16x8*)&BTl[(size_t)(n0 + r) * H_F + kc + j * 8];
        }
        __syncthreads();
        #pragma unroll
        for (int ks = 0; ks < 2; ++ks) {
            int k0 = ks * 32 + ksel;
            s16x8 a0h = *(const s16x8*)&Ah[(wr + rsel) * LDA2 + k0];
            s16x8 a1h = *(const s16x8*)&Ah[(wr + 16 + rsel) * LDA2 + k0];
            s16x8 a0l = *(const s16x8*)&Al[(wr + rsel) * LDA2 + k0];
            s16x8 a1l = *(const s16x8*)&Al[(wr + 16 + rsel) * LDA2 + k0];
            s16x8 b0h = *(const s16x8*)&Bh[(wc + rsel) * LDA2 + k0];
            s16x8 b1h = *(const s16x8*)&Bh[(wc + 16 + rsel) * LDA2 + k0];
            s16x8 b0l = *(const s16x8*)&Bl[(wc + rsel) * LDA2 + k0];
            s16x8 b1l = *(const s16x8*)&Bl[(wc + 16 + rsel) * LDA2 + k0];
            acc[0][0] = __builtin_amdgcn_mfma_f32_16x16x32_bf16(a0h, b0h, acc[0][0], 0, 0, 0);
            acc[0][0] = __builtin_amdgcn_mfma_f32_16x16x32_bf16(a0h, b0l, acc[0][0], 0, 0, 0);
            acc[0][0] = __builtin_amdgcn_mfma_f32_16x16x32_bf16(a0l, b0h, acc[0][0], 0, 0, 0);
            acc[0][1] = __builtin_amdgcn_mfma_f32_16x16x32_bf16(a0h, b1h, acc[0][1], 0, 0, 0);
            acc[0][1] = __builtin_amdgcn_mfma_f32_16x16x32_bf16(a0h, b1l, acc[0][1], 0, 0, 0);
            acc[0][1] = __builtin_amdgcn_mfma_f32_16x16x32_bf16(a0l, b1h, acc[0][1], 0, 0, 0);
            acc[1][0] = __builtin_amdgcn_mfma_f32_16x16x32_bf16(a1h, b0h, acc[1][0], 0, 0, 0);
            acc[1][0] = __builtin_amdgcn_mfma_f32_16x16x32_bf16(a1h, b0l, acc[1][0], 0, 0, 0);
            acc[1][0] = __builtin_amdgcn_mfma_f32_16x16x32_bf16(a1l, b0h, acc[1][0], 0, 0, 0);
            acc[1][1] = __builtin_amdgcn_mfma_f32_16x16x32_bf16(a1h, b1h, acc[1][1], 0, 0, 0);
            acc[1][1] = __builtin_amdgcn_mfma_f32_16x16x32_bf16(a1h, b1l, acc[1][1], 0, 0, 0);
            acc[1][1] = __builtin_amdgcn_mfma_f32_16x16x32_bf16(a1l, b1h, acc[1][1], 0, 0, 0);
        }
        __syncthreads();
    }
    int crow = (lane >> 4) * 4, ccol = lane & 15;
    #pragma unroll
    for (int mf = 0; mf < 2; ++mf)
        #pragma unroll
        for (int nf = 0; nf < 2; ++nf) {
            int col = n0 + wc + nf * 16 + ccol;
            #pragma unroll
            for (int i = 0; i < 4; ++i) {
                int gm = m0 + wr + mf * 16 + crow + i;
                if (gm < N_NODES) {
                    float* p = &out[(size_t)gm * H_F + col];
                    if (MODE == 0) {
                        *p = acc[mf][nf][i] + bias[col];
                    } else if (MODE == 1) {
                        *p += acc[mf][nf][i];
                    } else {
                        *p = fmaxf(*p + acc[mf][nf][i], 0.f);
                    }
                }
            }
        }
}

extern "C" void kernel_launch(void* const* d_in, const int* in_sizes, int n_in,
                              void* d_out, int out_size, void* d_ws, size_t ws_size,
                              hipStream_t stream) {
    const int* ei = (const int*)d_in[0];
    const int* rows = ei;
    const int* cols = ei + N_EDGES;
    const float* feat = (const float*)d_in[1];
    const float* Ws = (const float*)d_in[2];
    const float* bs = (const float*)d_in[3];
    const float* Wf = (const float*)d_in[4];
    const float* bf = (const float*)d_in[5];
    float* out = (float*)d_out;

    // workspace layout (~95 MB, all 16B-aligned)
    float* hA = (float*)d_ws;                              // 4,800,000 f32
    float* hB = hA + (size_t)N_NODES * IN_F;               // 4,800,000 f32
    ushort* nsh = (ushort*)(hB + (size_t)N_NODES * IN_F);  // 12,800,000 u16
    ushort* nsl = nsh + (size_t)N_NODES * H_F;             // 12,800,000 u16
    ushort* WsTh = nsl + (size_t)N_NODES * H_F;            // 98,304 u16
    ushort* WsTl = WsTh + N_NIE * IN_F * H_F;
    ushort* WfTh = WsTl + N_NIE * IN_F * H_F;              // 262,144 u16
    ushort* WfTl = WfTh + N_NIE * H_F * H_F;
    float* dinv = (float*)(WfTl + N_NIE * H_F * H_F);      // 50,000 f32
    int* rowptr = (int*)(dinv + N_NODES);                  // 50,004 i32
    int* csr_col = rowptr + 50004;                         // 800,000 i32
    int* bsum = csr_col + N_EDGES;                         // 256 i32
    int* boff = bsum + 256;                                // 256 i32
    // CSR-build temporaries aliased into nsh (consumed before nsh is written)
    int* cnt = (int*)nsh;
    int* cursor = cnt + N_NODES;

    hipMemsetAsync(cnt, 0, N_NODES * sizeof(int), stream);
    k_count<<<(N_EDGES + 255) / 256, 256, 0, stream>>>(rows, cols, cnt);
    k_scan1<<<SCAN_NB, 256, 0, stream>>>(cnt, rowptr, bsum);
    k_scan2<<<1, 256, 0, stream>>>(bsum, boff, rowptr);
    k_scan3<<<SCAN_NB, 256, 0, stream>>>(boff, rowptr, cursor);
    k_dinv<<<(N_NODES + 255) / 256, 256, 0, stream>>>(cnt, dinv);
    k_scatter<<<(N_EDGES + 255) / 256, 256, 0, stream>>>(rows, cols, cursor, csr_col);
    k_wsplit<<<(N_NIE * IN_F * H_F + 255) / 256, 256, 0, stream>>>(Ws, WsTh, WsTl, IN_F, H_F,
                                                                   N_NIE * IN_F * H_F);
    k_wsplit<<<(N_NIE * H_F * H_F + 255) / 256, 256, 0, stream>>>(Wf, WfTh, WfTl, H_F, H_F,
                                                                  N_NIE * H_F * H_F);
    k_norm<<<(N_NODES + 3) / 4, 256, 0, stream>>>(feat, hA);

    float* hcur = hA;
    float* hnext = hB;
    for (int i = 0; i < N_NIE; ++i) {
        k_mlp_mfma<<<dim3(782, 4), 256, 0, stream>>>(hcur, WsTh + (size_t)i * IN_F * H_F,
                                                     WsTl + (size_t)i * IN_F * H_F,
                                                     bs + (size_t)i * H_F, nsh, nsl);
        const ushort* fh = WfTh + (size_t)i * H_F * H_F;
        const ushort* fl = WfTl + (size_t)i * H_F * H_F;
        if (i == 0)
            k_fuse_mfma<0><<<dim3(782, 4), 256, 0, stream>>>(nsh, nsl, fh, fl, bf, out);
        else if (i < N_NIE - 1)
            k_fuse_mfma<1><<<dim3(782, 4), 256, 0, stream>>>(nsh, nsl, fh, fl, bf, out);
        else
            k_fuse_mfma<2><<<dim3(782, 4), 256, 0, stream>>>(nsh, nsl, fh, fl, bf, out);
        if (i < N_NIE - 1) {
            k_spmm_csr<<<(N_NODES * 32 + 255) / 256, 256, 0, stream>>>(rowptr, csr_col, dinv,
                                                                       hcur, hnext);
            float* t = hcur; hcur = hnext; hnext = t;
        }
    }
}